// Round 7
// baseline (488.913 us; speedup 1.0000x reference)
//
#include <hip/hip_runtime.h>
#include <math.h>

#define N_NODES 50000
#define N_EDGES 1600000
#define DIM 64
#define HEADS 8
#define EDGE_DIM 32
#define SCAN_NBLK 49  // ceil(50000/1024)

typedef __fp16 h2 __attribute__((ext_vector_type(2)));

// ---- bf16 helpers (RNE round via bit trick; inputs are finite) ----
__device__ __forceinline__ unsigned int f2bf(float f) {
    union { float f; unsigned int u; } c; c.f = f;
    unsigned int u = c.u;
    return (u + 0x7FFFu + ((u >> 16) & 1u)) >> 16;
}
__device__ __forceinline__ float bf_lo(unsigned int u) { return __uint_as_float(u << 16); }
__device__ __forceinline__ float bf_hi(unsigned int u) { return __uint_as_float(u & 0xFFFF0000u); }

// ---------------- K_prep: pack MLP weights as half2 pairs (k-pairs) ----------------
__global__ __launch_bounds__(1024) void pack_weights(
    const float* __restrict__ We1, const float* __restrict__ We2,
    h2* __restrict__ w1p, h2* __restrict__ w2p)
{
    const int t = threadIdx.x;
    if (t < 512) {
        const int c = t >> 4, kk = t & 15;
        w1p[t] = __builtin_amdgcn_cvt_pkrtz(We1[(2 * kk) * EDGE_DIM + c],
                                            We1[(2 * kk + 1) * EDGE_DIM + c]);
    } else if (t < 512 + 128) {
        const int u = t - 512;
        const int h = u >> 4, cc = u & 15;
        w2p[u] = __builtin_amdgcn_cvt_pkrtz(We2[(2 * cc) * HEADS + h],
                                            We2[(2 * cc + 1) * HEADS + h]);
    }
}

// ---------------- K0a: histogram of destination degrees (x4 vectorized) ----------------
__global__ __launch_bounds__(256) void count_deg(
    const int* __restrict__ ei, int* __restrict__ deg)
{
    const int e4 = blockIdx.x * 256 + threadIdx.x;
    if (e4 < N_EDGES / 4) {
        const int4 v = ((const int4*)(ei + N_EDGES))[e4];
        atomicAdd(&deg[v.x], 1);
        atomicAdd(&deg[v.y], 1);
        atomicAdd(&deg[v.z], 1);
        atomicAdd(&deg[v.w], 1);
    }
}

// ---------------- K0b: hierarchical exclusive scan ----------------
__global__ __launch_bounds__(1024) void scan_local(
    const int* __restrict__ deg, int* __restrict__ off, int* __restrict__ part)
{
    __shared__ int s[1024];
    const int tid = threadIdx.x;
    const int idx = blockIdx.x * 1024 + tid;
    s[tid] = (idx < N_NODES) ? deg[idx] : 0;
    __syncthreads();
    for (int o = 1; o < 1024; o <<= 1) {
        int t = (tid >= o) ? s[tid - o] : 0;
        __syncthreads();
        s[tid] += t;
        __syncthreads();
    }
    if (idx < N_NODES) off[idx + 1] = s[tid];
    if (tid == 1023) part[blockIdx.x] = s[1023];
}

__global__ __launch_bounds__(64) void scan_part(int* __restrict__ part)
{
    const int lane = threadIdx.x;
    int v = (lane < SCAN_NBLK) ? part[lane] : 0;
    const int orig = v;
    for (int o = 1; o < 64; o <<= 1) {
        int t = __shfl_up(v, o, 64);
        if (lane >= o) v += t;
    }
    if (lane < SCAN_NBLK) part[lane] = v - orig;
}

__global__ __launch_bounds__(1024) void scan_add(
    const int* __restrict__ part, int* __restrict__ off, int* __restrict__ woff)
{
    const int idx = blockIdx.x * 1024 + threadIdx.x;
    if (idx == 0) { off[0] = 0; woff[0] = 0; }
    if (idx < N_NODES) {
        const int val = off[idx + 1] + part[blockIdx.x];
        off[idx + 1] = val;
        if (idx + 1 < N_NODES) woff[idx + 1] = val;
    }
}

// ---------------- K1: Q/K/V projections; K,V packed bf16 into one uint row ----------------
__global__ __launch_bounds__(256) void qkv_proj(
    const float* __restrict__ x,
    const float* __restrict__ WQ, const float* __restrict__ bQ,
    const float* __restrict__ WK, const float* __restrict__ bK,
    const float* __restrict__ WV, const float* __restrict__ bV,
    float* __restrict__ Q, unsigned int* __restrict__ KV)
{
    __shared__ float sWQ[DIM * DIM];
    __shared__ float sWK[DIM * DIM];
    __shared__ float sWV[DIM * DIM];
    for (int t = threadIdx.x; t < DIM * DIM; t += blockDim.x) {
        sWQ[t] = WQ[t]; sWK[t] = WK[t]; sWV[t] = WV[t];
    }
    __syncthreads();
    const int lane = threadIdx.x & 63;
    const int wave = threadIdx.x >> 6;
    const int n = blockIdx.x * 4 + wave;
    if (n >= N_NODES) return;
    float xl = x[(size_t)n * DIM + lane];
    float aq = bQ[lane], ak = bK[lane], av = bV[lane];
    #pragma unroll
    for (int k = 0; k < DIM; ++k) {
        float xv = __shfl(xl, k, 64);
        aq += xv * sWQ[k * DIM + lane];
        ak += xv * sWK[k * DIM + lane];
        av += xv * sWV[k * DIM + lane];
    }
    Q[(size_t)n * DIM + lane] = aq;
    KV[(size_t)n * DIM + lane] = f2bf(ak) | (f2bf(av) << 16);  // K lo, V hi
}

// ---------------- K2a: CSR permutation scatter — ONLY 8B random writes ----------------
__global__ __launch_bounds__(256) void scatter_perm(
    const int* __restrict__ ei, int* __restrict__ woff, uint2* __restrict__ ps)
{
    const int e = blockIdx.x * 256 + threadIdx.x;
    if (e >= N_EDGES) return;
    const int i = ei[e];
    const int j = ei[N_EDGES + e];
    const int p = atomicAdd(&woff[j], 1);
    ps[p] = make_uint2((unsigned int)e, (unsigned int)i);
}

// ---------------- K2b: per-edge MLP, fully streamed (random edge_attr row READS,
// coalesced bias WRITES at sorted position) ----------------
__global__ __launch_bounds__(256) void edge_mlp(
    const uint2* __restrict__ ps,
    const float* __restrict__ edge_attr,
    const h2* __restrict__ w1p, const float* __restrict__ be1,
    const h2* __restrict__ w2p, const float* __restrict__ be2,
    uint4* __restrict__ bias_sorted)
{
    const int p = blockIdx.x * 256 + threadIdx.x;
    if (p >= N_EDGES) return;
    const unsigned int e = ps[p].x;
    float a[EDGE_DIM];
    const float4* ar = (const float4*)(edge_attr + (size_t)e * EDGE_DIM);
    #pragma unroll
    for (int q = 0; q < EDGE_DIM / 4; ++q) {
        float4 v = ar[q];
        a[q * 4 + 0] = v.x; a[q * 4 + 1] = v.y;
        a[q * 4 + 2] = v.z; a[q * 4 + 3] = v.w;
    }
    h2 a2[EDGE_DIM / 2];
    #pragma unroll
    for (int kk = 0; kk < EDGE_DIM / 2; ++kk)
        a2[kk] = __builtin_amdgcn_cvt_pkrtz(a[2 * kk], a[2 * kk + 1]);
    float sil[EDGE_DIM];
    #pragma unroll 8
    for (int c = 0; c < EDGE_DIM; ++c) {
        float s = be1[c];
        #pragma unroll
        for (int kk = 0; kk < EDGE_DIM / 2; ++kk)
            s = __builtin_amdgcn_fdot2(a2[kk], w1p[c * 16 + kk], s, false);
        sil[c] = __fdividef(s, 1.0f + __expf(-s));
    }
    h2 s2[EDGE_DIM / 2];
    #pragma unroll
    for (int cc = 0; cc < EDGE_DIM / 2; ++cc)
        s2[cc] = __builtin_amdgcn_cvt_pkrtz(sil[2 * cc], sil[2 * cc + 1]);
    float bias[HEADS];
    #pragma unroll
    for (int h = 0; h < HEADS; ++h) {
        float b = be2[h];
        #pragma unroll
        for (int cc = 0; cc < EDGE_DIM / 2; ++cc)
            b = __builtin_amdgcn_fdot2(s2[cc], w2p[h * 16 + cc], b, false);
        bias[h] = b;
    }
    uint4 br;
    br.x = f2bf(bias[0]) | (f2bf(bias[1]) << 16);
    br.y = f2bf(bias[2]) | (f2bf(bias[3]) << 16);
    br.z = f2bf(bias[4]) | (f2bf(bias[5]) << 16);
    br.w = f2bf(bias[6]) | (f2bf(bias[7]) << 16);
    bias_sorted[p] = br;
}

// ---------------- K3: per-node attention + fused output projection ----------------
__global__ __launch_bounds__(256) void node_attn_out(
    const int* __restrict__ off,
    const uint2* __restrict__ ps,
    const unsigned short* __restrict__ bias_u16,
    const float* __restrict__ Q, const unsigned int* __restrict__ KV,
    const float* __restrict__ WO, const float* __restrict__ bO,
    float* __restrict__ out)
{
    __shared__ float sWO[DIM * DIM];
    for (int t = threadIdx.x; t < DIM * DIM; t += 256) sWO[t] = WO[t];
    __syncthreads();
    const int lane = threadIdx.x & 63;
    const int wave = threadIdx.x >> 6;
    const int j = blockIdx.x * 4 + wave;
    if (j >= N_NODES) return;
    const int beg = off[j], end = off[j + 1];
    const int h = lane >> 3;
    const float qv = Q[(size_t)j * DIM + lane];
    const float inv_sqrt_dk = 0.35355339059327373f;
    float num = 0.0f;
    float den = 1e-12f;
    int t = beg;
    for (; t + 3 < end; t += 4) {
        const int i0 = (int)ps[t + 0].y;
        const int i1 = (int)ps[t + 1].y;
        const int i2 = (int)ps[t + 2].y;
        const int i3 = (int)ps[t + 3].y;
        const unsigned int u0 = KV[(size_t)i0 * DIM + lane];
        const unsigned int u1 = KV[(size_t)i1 * DIM + lane];
        const unsigned int u2 = KV[(size_t)i2 * DIM + lane];
        const unsigned int u3 = KV[(size_t)i3 * DIM + lane];
        const float b0 = bf_lo((unsigned int)bias_u16[(size_t)(t + 0) * HEADS + h]);
        const float b1 = bf_lo((unsigned int)bias_u16[(size_t)(t + 1) * HEADS + h]);
        const float b2 = bf_lo((unsigned int)bias_u16[(size_t)(t + 2) * HEADS + h]);
        const float b3 = bf_lo((unsigned int)bias_u16[(size_t)(t + 3) * HEADS + h]);
        float d0 = qv * bf_lo(u0);
        float d1 = qv * bf_lo(u1);
        float d2 = qv * bf_lo(u2);
        float d3 = qv * bf_lo(u3);
        d0 += __shfl_xor(d0, 1, 64); d1 += __shfl_xor(d1, 1, 64);
        d2 += __shfl_xor(d2, 1, 64); d3 += __shfl_xor(d3, 1, 64);
        d0 += __shfl_xor(d0, 2, 64); d1 += __shfl_xor(d1, 2, 64);
        d2 += __shfl_xor(d2, 2, 64); d3 += __shfl_xor(d3, 2, 64);
        d0 += __shfl_xor(d0, 4, 64); d1 += __shfl_xor(d1, 4, 64);
        d2 += __shfl_xor(d2, 4, 64); d3 += __shfl_xor(d3, 4, 64);
        const float e0 = __expf(d0 * inv_sqrt_dk + b0);
        const float e1 = __expf(d1 * inv_sqrt_dk + b1);
        const float e2 = __expf(d2 * inv_sqrt_dk + b2);
        const float e3 = __expf(d3 * inv_sqrt_dk + b3);
        num += e0 * bf_hi(u0) + e1 * bf_hi(u1) + e2 * bf_hi(u2) + e3 * bf_hi(u3);
        den += e0 + e1 + e2 + e3;
    }
    for (; t < end; ++t) {
        const int i0 = (int)ps[t].y;
        const unsigned int u0 = KV[(size_t)i0 * DIM + lane];
        const float b0 = bf_lo((unsigned int)bias_u16[(size_t)t * HEADS + h]);
        float d0 = qv * bf_lo(u0);
        d0 += __shfl_xor(d0, 1, 64);
        d0 += __shfl_xor(d0, 2, 64);
        d0 += __shfl_xor(d0, 4, 64);
        const float e0 = __expf(d0 * inv_sqrt_dk + b0);
        num += e0 * bf_hi(u0);
        den += e0;
    }
    const float av = num / den;
    float acc = bO[lane];
    #pragma unroll
    for (int k = 0; k < DIM; ++k) {
        acc += __shfl(av, k, 64) * sWO[k * DIM + lane];
    }
    out[(size_t)j * DIM + lane] = acc;
}

extern "C" void kernel_launch(void* const* d_in, const int* in_sizes, int n_in,
                              void* d_out, int out_size, void* d_ws, size_t ws_size,
                              hipStream_t stream) {
    const float* x    = (const float*)d_in[0];
    const int*   ei   = (const int*)d_in[1];
    const float* ea   = (const float*)d_in[2];
    const float* WQ   = (const float*)d_in[3];
    const float* bQ   = (const float*)d_in[4];
    const float* WK   = (const float*)d_in[5];
    const float* bK   = (const float*)d_in[6];
    const float* WV   = (const float*)d_in[7];
    const float* bV   = (const float*)d_in[8];
    const float* WO   = (const float*)d_in[9];
    const float* bO   = (const float*)d_in[10];
    const float* We1  = (const float*)d_in[11];
    const float* be1  = (const float*)d_in[12];
    const float* We2  = (const float*)d_in[13];
    const float* be2  = (const float*)d_in[14];
    float* out = (float*)d_out;

    char* ws = (char*)d_ws;
    size_t off_b = 0;
    auto alloc = [&](size_t bytes) {
        void* p = ws + off_b;
        off_b += (bytes + 255) & ~(size_t)255;
        return p;
    };
    float*        Q           = (float*)alloc((size_t)N_NODES * DIM * sizeof(float));
    unsigned int* KV          = (unsigned int*)alloc((size_t)N_NODES * DIM * sizeof(unsigned int));
    uint4*        bias_sorted = (uint4*)alloc((size_t)N_EDGES * sizeof(uint4));
    uint2*        ps          = (uint2*)alloc((size_t)N_EDGES * sizeof(uint2));
    int*          deg         = (int*)alloc((size_t)N_NODES * sizeof(int));
    int*          offs        = (int*)alloc((size_t)(N_NODES + 1) * sizeof(int));
    int*          woff        = (int*)alloc((size_t)N_NODES * sizeof(int));
    int*          part        = (int*)alloc((size_t)SCAN_NBLK * sizeof(int));
    h2*           w1p         = (h2*)alloc(512 * sizeof(h2));
    h2*           w2p         = (h2*)alloc(128 * sizeof(h2));

    (void)hipMemsetAsync(deg, 0, (size_t)N_NODES * sizeof(int), stream);

    pack_weights<<<1, 1024, 0, stream>>>(We1, We2, w1p, w2p);
    count_deg<<<(N_EDGES / 4 + 255) / 256, 256, 0, stream>>>(ei, deg);
    scan_local<<<SCAN_NBLK, 1024, 0, stream>>>(deg, offs, part);
    scan_part<<<1, 64, 0, stream>>>(part);
    scan_add<<<SCAN_NBLK, 1024, 0, stream>>>(part, offs, woff);
    qkv_proj<<<(N_NODES + 3) / 4, 256, 0, stream>>>(x, WQ, bQ, WK, bK, WV, bV, Q, KV);
    scatter_perm<<<N_EDGES / 256, 256, 0, stream>>>(ei, woff, ps);
    edge_mlp<<<N_EDGES / 256, 256, 0, stream>>>(ps, ea, w1p, be1, w2p, be2, bias_sorted);
    node_attn_out<<<(N_NODES + 3) / 4, 256, 0, stream>>>(offs, ps,
                                                         (const unsigned short*)bias_sorted,
                                                         Q, KV, WO, bO, out);
}

// Round 8
// 447.233 us; speedup vs baseline: 1.0932x; 1.0932x over previous
//
#include <hip/hip_runtime.h>
#include <math.h>

#define N_NODES 50000
#define N_EDGES 1600000
#define DIM 64
#define HEADS 8
#define EDGE_DIM 32

#define NB 256        // destination buckets
#define NPB 196       // nodes per bucket (196*256 = 50176 >= 50000)
#define ACAP 8192     // per-bucket region capacity (mean 6272, sd 79 -> 24 sigma)
#define CSR_CAP 7680  // LDS CSR capacity (17.8 sigma above mean)

typedef __fp16 h2 __attribute__((ext_vector_type(2)));

// ---- bf16 helpers (RNE round via bit trick; inputs are finite) ----
__device__ __forceinline__ unsigned int f2bf(float f) {
    union { float f; unsigned int u; } c; c.f = f;
    unsigned int u = c.u;
    return (u + 0x7FFFu + ((u >> 16) & 1u)) >> 16;
}
__device__ __forceinline__ float bf_lo(unsigned int u) { return __uint_as_float(u << 16); }
__device__ __forceinline__ float bf_hi(unsigned int u) { return __uint_as_float(u & 0xFFFF0000u); }

// ---------------- K_prep: pack MLP weights as half2 pairs ----------------
__global__ __launch_bounds__(1024) void pack_weights(
    const float* __restrict__ We1, const float* __restrict__ We2,
    h2* __restrict__ w1p, h2* __restrict__ w2p)
{
    const int t = threadIdx.x;
    if (t < 512) {
        const int c = t >> 4, kk = t & 15;
        w1p[t] = __builtin_amdgcn_cvt_pkrtz(We1[(2 * kk) * EDGE_DIM + c],
                                            We1[(2 * kk + 1) * EDGE_DIM + c]);
    } else if (t < 512 + 128) {
        const int u = t - 512;
        const int h = u >> 4, cc = u & 15;
        w2p[u] = __builtin_amdgcn_cvt_pkrtz(We2[(2 * cc) * HEADS + h],
                                            We2[(2 * cc + 1) * HEADS + h]);
    }
}

// ---------------- K_A: bucket partition ----------------
// Per block: LDS histogram of its 16K edges over 256 buckets, one global
// atomic reservation per bucket, then scatter {e,j} into per-bucket regions.
// Write frontier = 256 cursors -> L2/L3 resident, no sector waste.
__global__ __launch_bounds__(512) void bucket_partition(
    const int* __restrict__ ei, int* __restrict__ gcur, uint2* __restrict__ A)
{
    __shared__ int cnt[NB];
    __shared__ int base[NB];
    const int tid = threadIdx.x;
    if (tid < NB) cnt[tid] = 0;
    __syncthreads();
    const int e0 = blockIdx.x * (512 * 32);
    for (int k = 0; k < 32; ++k) {
        const int e = e0 + k * 512 + tid;
        if (e < N_EDGES) atomicAdd(&cnt[ei[N_EDGES + e] / NPB], 1);
    }
    __syncthreads();
    if (tid < NB) {
        base[tid] = atomicAdd(&gcur[tid], cnt[tid]);
        cnt[tid] = 0;  // reuse as local cursor
    }
    __syncthreads();
    for (int k = 0; k < 32; ++k) {
        const int e = e0 + k * 512 + tid;
        if (e < N_EDGES) {
            const int j = ei[N_EDGES + e];
            const int b = j / NPB;
            const int lp = base[b] + atomicAdd(&cnt[b], 1);
            if (lp < ACAP)
                A[(size_t)b * ACAP + lp] = make_uint2((unsigned)e, (unsigned)j);
        }
    }
}

// ---------------- K1: Q/K/V projections; K,V packed bf16 into one uint row ----------------
__global__ __launch_bounds__(256) void qkv_proj(
    const float* __restrict__ x,
    const float* __restrict__ WQ, const float* __restrict__ bQ,
    const float* __restrict__ WK, const float* __restrict__ bK,
    const float* __restrict__ WV, const float* __restrict__ bV,
    float* __restrict__ Q, unsigned int* __restrict__ KV)
{
    __shared__ float sWQ[DIM * DIM];
    __shared__ float sWK[DIM * DIM];
    __shared__ float sWV[DIM * DIM];
    for (int t = threadIdx.x; t < DIM * DIM; t += blockDim.x) {
        sWQ[t] = WQ[t]; sWK[t] = WK[t]; sWV[t] = WV[t];
    }
    __syncthreads();
    const int lane = threadIdx.x & 63;
    const int wave = threadIdx.x >> 6;
    const int n = blockIdx.x * 4 + wave;
    if (n >= N_NODES) return;
    float xl = x[(size_t)n * DIM + lane];
    float aq = bQ[lane], ak = bK[lane], av = bV[lane];
    #pragma unroll
    for (int k = 0; k < DIM; ++k) {
        float xv = __shfl(xl, k, 64);
        aq += xv * sWQ[k * DIM + lane];
        ak += xv * sWK[k * DIM + lane];
        av += xv * sWV[k * DIM + lane];
    }
    Q[(size_t)n * DIM + lane] = aq;
    KV[(size_t)n * DIM + lane] = f2bf(ak) | (f2bf(av) << 16);  // K lo, V hi
}

// ---------------- K_B: per-bucket CSR-in-LDS + MLP + attention + out-proj ----------------
// One block per bucket (1 block/CU). All edges of a node live in this bucket.
__global__ __launch_bounds__(1024, 1) void bucket_attn(
    const int* __restrict__ gcur, const uint2* __restrict__ A,
    const int* __restrict__ ei,
    const float* __restrict__ edge_attr,
    const h2* __restrict__ w1p, const float* __restrict__ be1,
    const h2* __restrict__ w2p, const float* __restrict__ be2,
    const float* __restrict__ Q, const unsigned int* __restrict__ KV,
    const float* __restrict__ WO, const float* __restrict__ bO,
    float* __restrict__ out)
{
    __shared__ int lds_i[CSR_CAP];                      // 30 KB
    __shared__ unsigned short lds_b16[CSR_CAP * HEADS]; // 120 KB
    __shared__ int ldeg[NPB];
    __shared__ int loff[NPB + 1];
    __shared__ int sc[256];
    const int tid = threadIdx.x;
    const int b = blockIdx.x;
    const int jbase = b * NPB;
    int nb = gcur[b]; if (nb > ACAP) nb = ACAP;
    if (tid < NPB) ldeg[tid] = 0;
    __syncthreads();
    // 1) degree histogram
    for (int r = tid; r < nb; r += 1024)
        atomicAdd(&ldeg[(int)A[(size_t)b * ACAP + r].y - jbase], 1);
    __syncthreads();
    // 2) 256-wide Hillis-Steele scan -> local CSR offsets
    if (tid < 256) sc[tid] = (tid < NPB) ? ldeg[tid] : 0;
    __syncthreads();
    for (int o = 1; o < 256; o <<= 1) {
        int t = 0;
        if (tid < 256 && tid >= o) t = sc[tid - o];
        __syncthreads();
        if (tid < 256) sc[tid] += t;
        __syncthreads();
    }
    if (tid == 0) loff[0] = 0;
    if (tid < NPB) { loff[tid + 1] = sc[tid]; ldeg[tid] = 0; }  // ldeg -> cursor
    __syncthreads();
    // 3) build pass: MLP per edge, place {i, bias} into LDS CSR slot
    for (int r = tid; r < nb; r += 1024) {
        const uint2 rec = A[(size_t)b * ACAP + r];
        const int e = (int)rec.x;
        const int jl = (int)rec.y - jbase;
        const int slot = loff[jl] + atomicAdd(&ldeg[jl], 1);
        // MLP: 32 -> 32 SiLU -> 8, f16 dot2, weights via scalar pipe
        float a[EDGE_DIM];
        const float4* ar = (const float4*)(edge_attr + (size_t)e * EDGE_DIM);
        #pragma unroll
        for (int q = 0; q < EDGE_DIM / 4; ++q) {
            float4 v = ar[q];
            a[q * 4 + 0] = v.x; a[q * 4 + 1] = v.y;
            a[q * 4 + 2] = v.z; a[q * 4 + 3] = v.w;
        }
        h2 a2[EDGE_DIM / 2];
        #pragma unroll
        for (int kk = 0; kk < EDGE_DIM / 2; ++kk)
            a2[kk] = __builtin_amdgcn_cvt_pkrtz(a[2 * kk], a[2 * kk + 1]);
        float sil[EDGE_DIM];
        #pragma unroll 8
        for (int c = 0; c < EDGE_DIM; ++c) {
            float s = be1[c];
            #pragma unroll
            for (int kk = 0; kk < EDGE_DIM / 2; ++kk)
                s = __builtin_amdgcn_fdot2(a2[kk], w1p[c * 16 + kk], s, false);
            sil[c] = __fdividef(s, 1.0f + __expf(-s));
        }
        h2 s2[EDGE_DIM / 2];
        #pragma unroll
        for (int cc = 0; cc < EDGE_DIM / 2; ++cc)
            s2[cc] = __builtin_amdgcn_cvt_pkrtz(sil[2 * cc], sil[2 * cc + 1]);
        unsigned short bh[HEADS];
        #pragma unroll
        for (int h = 0; h < HEADS; ++h) {
            float bias = be2[h];
            #pragma unroll
            for (int cc = 0; cc < EDGE_DIM / 2; ++cc)
                bias = __builtin_amdgcn_fdot2(s2[cc], w2p[h * 16 + cc], bias, false);
            bh[h] = (unsigned short)f2bf(bias);
        }
        if (slot < CSR_CAP) {
            lds_i[slot] = ei[e];
            #pragma unroll
            for (int h = 0; h < HEADS; ++h) lds_b16[slot * HEADS + h] = bh[h];
        }
    }
    __syncthreads();
    // 4) attention + fused WO projection, one wave per node
    const int lane = tid & 63;
    const int wave = tid >> 6;  // 0..15
    const int h = lane >> 3;
    const float inv_sqrt_dk = 0.35355339059327373f;
    for (int n = wave; n < NPB; n += 16) {
        const int j = jbase + n;
        if (j >= N_NODES) break;
        const int beg = loff[n], end = loff[n + 1];
        const float qv = Q[(size_t)j * DIM + lane];
        float num = 0.0f, den = 1e-12f;
        int t = beg;
        for (; t + 3 < end; t += 4) {
            const int i0 = lds_i[t + 0];
            const int i1 = lds_i[t + 1];
            const int i2 = lds_i[t + 2];
            const int i3 = lds_i[t + 3];
            const unsigned int u0 = KV[(size_t)i0 * DIM + lane];
            const unsigned int u1 = KV[(size_t)i1 * DIM + lane];
            const unsigned int u2 = KV[(size_t)i2 * DIM + lane];
            const unsigned int u3 = KV[(size_t)i3 * DIM + lane];
            const float b0 = bf_lo((unsigned int)lds_b16[(t + 0) * HEADS + h]);
            const float b1 = bf_lo((unsigned int)lds_b16[(t + 1) * HEADS + h]);
            const float b2 = bf_lo((unsigned int)lds_b16[(t + 2) * HEADS + h]);
            const float b3 = bf_lo((unsigned int)lds_b16[(t + 3) * HEADS + h]);
            float d0 = qv * bf_lo(u0);
            float d1 = qv * bf_lo(u1);
            float d2 = qv * bf_lo(u2);
            float d3 = qv * bf_lo(u3);
            d0 += __shfl_xor(d0, 1, 64); d1 += __shfl_xor(d1, 1, 64);
            d2 += __shfl_xor(d2, 1, 64); d3 += __shfl_xor(d3, 1, 64);
            d0 += __shfl_xor(d0, 2, 64); d1 += __shfl_xor(d1, 2, 64);
            d2 += __shfl_xor(d2, 2, 64); d3 += __shfl_xor(d3, 2, 64);
            d0 += __shfl_xor(d0, 4, 64); d1 += __shfl_xor(d1, 4, 64);
            d2 += __shfl_xor(d2, 4, 64); d3 += __shfl_xor(d3, 4, 64);
            const float e0 = __expf(d0 * inv_sqrt_dk + b0);
            const float e1 = __expf(d1 * inv_sqrt_dk + b1);
            const float e2 = __expf(d2 * inv_sqrt_dk + b2);
            const float e3 = __expf(d3 * inv_sqrt_dk + b3);
            num += e0 * bf_hi(u0) + e1 * bf_hi(u1) + e2 * bf_hi(u2) + e3 * bf_hi(u3);
            den += e0 + e1 + e2 + e3;
        }
        for (; t < end; ++t) {
            const int i0 = lds_i[t];
            const unsigned int u0 = KV[(size_t)i0 * DIM + lane];
            const float b0 = bf_lo((unsigned int)lds_b16[t * HEADS + h]);
            float d0 = qv * bf_lo(u0);
            d0 += __shfl_xor(d0, 1, 64);
            d0 += __shfl_xor(d0, 2, 64);
            d0 += __shfl_xor(d0, 4, 64);
            const float e0 = __expf(d0 * inv_sqrt_dk + b0);
            num += e0 * bf_hi(u0);
            den += e0;
        }
        const float av = num / den;
        // WO via L1 (16 KB, resident after first node)
        float acc = bO[lane];
        #pragma unroll
        for (int k = 0; k < DIM; ++k)
            acc += __shfl(av, k, 64) * WO[k * DIM + lane];
        out[(size_t)j * DIM + lane] = acc;
    }
}

extern "C" void kernel_launch(void* const* d_in, const int* in_sizes, int n_in,
                              void* d_out, int out_size, void* d_ws, size_t ws_size,
                              hipStream_t stream) {
    const float* x    = (const float*)d_in[0];
    const int*   ei   = (const int*)d_in[1];
    const float* ea   = (const float*)d_in[2];
    const float* WQ   = (const float*)d_in[3];
    const float* bQ   = (const float*)d_in[4];
    const float* WK   = (const float*)d_in[5];
    const float* bK   = (const float*)d_in[6];
    const float* WV   = (const float*)d_in[7];
    const float* bV   = (const float*)d_in[8];
    const float* WO   = (const float*)d_in[9];
    const float* bO   = (const float*)d_in[10];
    const float* We1  = (const float*)d_in[11];
    const float* be1  = (const float*)d_in[12];
    const float* We2  = (const float*)d_in[13];
    const float* be2  = (const float*)d_in[14];
    float* out = (float*)d_out;

    char* ws = (char*)d_ws;
    size_t off_b = 0;
    auto alloc = [&](size_t bytes) {
        void* p = ws + off_b;
        off_b += (bytes + 255) & ~(size_t)255;
        return p;
    };
    float*        Q    = (float*)alloc((size_t)N_NODES * DIM * sizeof(float));
    unsigned int* KV   = (unsigned int*)alloc((size_t)N_NODES * DIM * sizeof(unsigned int));
    uint2*        A    = (uint2*)alloc((size_t)NB * ACAP * sizeof(uint2));
    int*          gcur = (int*)alloc((size_t)NB * sizeof(int));
    h2*           w1p  = (h2*)alloc(512 * sizeof(h2));
    h2*           w2p  = (h2*)alloc(128 * sizeof(h2));

    (void)hipMemsetAsync(gcur, 0, (size_t)NB * sizeof(int), stream);

    pack_weights<<<1, 1024, 0, stream>>>(We1, We2, w1p, w2p);
    bucket_partition<<<(N_EDGES + 512 * 32 - 1) / (512 * 32), 512, 0, stream>>>(ei, gcur, A);
    qkv_proj<<<(N_NODES + 3) / 4, 256, 0, stream>>>(x, WQ, bQ, WK, bK, WV, bV, Q, KV);
    bucket_attn<<<NB, 1024, 0, stream>>>(gcur, A, ei, ea, w1p, be1, w2p, be2,
                                         Q, KV, WO, bO, out);
}

// Round 9
// 365.267 us; speedup vs baseline: 1.3385x; 1.2244x over previous
//
#include <hip/hip_runtime.h>
#include <math.h>

#define N_NODES 50000
#define N_EDGES 1600000
#define DIM 64
#define HEADS 8
#define EDGE_DIM 32

#define NB 256      // destination buckets
#define NPB 196     // nodes per bucket (196*256 = 50176 >= 50000)
#define ACAP 8192   // per-bucket region capacity (mean 6250, sd ~79 -> 24 sigma)
#define EPT 8       // edges per thread in partition
#define PART_T 512
#define PART_E (PART_T * EPT)  // 4096 edges per block

typedef __fp16 h2 __attribute__((ext_vector_type(2)));

// ---- bf16 helpers (RNE round via bit trick; inputs are finite) ----
__device__ __forceinline__ unsigned int f2bf(float f) {
    union { float f; unsigned int u; } c; c.f = f;
    unsigned int u = c.u;
    return (u + 0x7FFFu + ((u >> 16) & 1u)) >> 16;
}
__device__ __forceinline__ float bf_lo(unsigned int u) { return __uint_as_float(u << 16); }
__device__ __forceinline__ float bf_hi(unsigned int u) { return __uint_as_float(u & 0xFFFF0000u); }

// ---------------- K_prep: pack MLP weights as half2 pairs ----------------
__global__ __launch_bounds__(1024) void pack_weights(
    const float* __restrict__ We1, const float* __restrict__ We2,
    h2* __restrict__ w1p, h2* __restrict__ w2p)
{
    const int t = threadIdx.x;
    if (t < 512) {
        const int c = t >> 4, kk = t & 15;
        w1p[t] = __builtin_amdgcn_cvt_pkrtz(We1[(2 * kk) * EDGE_DIM + c],
                                            We1[(2 * kk + 1) * EDGE_DIM + c]);
    } else if (t < 512 + 128) {
        const int u = t - 512;
        const int h = u >> 4, cc = u & 15;
        w2p[u] = __builtin_amdgcn_cvt_pkrtz(We2[(2 * cc) * HEADS + h],
                                            We2[(2 * cc + 1) * HEADS + h]);
    }
}

// ---------------- K_A: MLP + bucket partition ----------------
// Streams ei + edge_attr (coalesced), computes the edge MLP, writes
// {jl<<24|i, bias[8]bf16} into per-bucket regions. Write frontier is
// block-reserved sequential chunks -> full-line writes, L2-resident.
__global__ __launch_bounds__(512) void mlp_partition(
    const int* __restrict__ ei,
    const float* __restrict__ edge_attr,
    const h2* __restrict__ w1p, const float* __restrict__ be1,
    const h2* __restrict__ w2p, const float* __restrict__ be2,
    int* __restrict__ gcur,
    unsigned int* __restrict__ A_rec, uint4* __restrict__ A_bias)
{
    __shared__ int cnt[NB];
    __shared__ int base[NB];
    const int tid = threadIdx.x;
    if (tid < NB) cnt[tid] = 0;
    __syncthreads();
    const int e0 = blockIdx.x * PART_E;
    #pragma unroll
    for (int k = 0; k < EPT; ++k) {
        const int e = e0 + k * PART_T + tid;
        if (e < N_EDGES) atomicAdd(&cnt[ei[N_EDGES + e] / NPB], 1);
    }
    __syncthreads();
    if (tid < NB) {
        base[tid] = atomicAdd(&gcur[tid], cnt[tid]);
        cnt[tid] = 0;  // reuse as local cursor
    }
    __syncthreads();
    for (int k = 0; k < EPT; ++k) {
        const int e = e0 + k * PART_T + tid;
        if (e >= N_EDGES) break;
        const int i = ei[e];
        const int j = ei[N_EDGES + e];
        const int b = j / NPB;
        const int jl = j - b * NPB;
        // MLP: 32 -> 32 SiLU -> 8, f16 dot2, weights via scalar pipe
        float a[EDGE_DIM];
        const float4* ar = (const float4*)(edge_attr + (size_t)e * EDGE_DIM);
        #pragma unroll
        for (int q = 0; q < EDGE_DIM / 4; ++q) {
            float4 v = ar[q];
            a[q * 4 + 0] = v.x; a[q * 4 + 1] = v.y;
            a[q * 4 + 2] = v.z; a[q * 4 + 3] = v.w;
        }
        h2 a2[EDGE_DIM / 2];
        #pragma unroll
        for (int kk = 0; kk < EDGE_DIM / 2; ++kk)
            a2[kk] = __builtin_amdgcn_cvt_pkrtz(a[2 * kk], a[2 * kk + 1]);
        float sil[EDGE_DIM];
        #pragma unroll 8
        for (int c = 0; c < EDGE_DIM; ++c) {
            float s = be1[c];
            #pragma unroll
            for (int kk = 0; kk < EDGE_DIM / 2; ++kk)
                s = __builtin_amdgcn_fdot2(a2[kk], w1p[c * 16 + kk], s, false);
            sil[c] = __fdividef(s, 1.0f + __expf(-s));
        }
        h2 s2[EDGE_DIM / 2];
        #pragma unroll
        for (int cc = 0; cc < EDGE_DIM / 2; ++cc)
            s2[cc] = __builtin_amdgcn_cvt_pkrtz(sil[2 * cc], sil[2 * cc + 1]);
        uint4 br;
        float b0f = be2[0], b1f = be2[1], b2f = be2[2], b3f = be2[3];
        float b4f = be2[4], b5f = be2[5], b6f = be2[6], b7f = be2[7];
        #pragma unroll
        for (int cc = 0; cc < EDGE_DIM / 2; ++cc) {
            b0f = __builtin_amdgcn_fdot2(s2[cc], w2p[0 * 16 + cc], b0f, false);
            b1f = __builtin_amdgcn_fdot2(s2[cc], w2p[1 * 16 + cc], b1f, false);
            b2f = __builtin_amdgcn_fdot2(s2[cc], w2p[2 * 16 + cc], b2f, false);
            b3f = __builtin_amdgcn_fdot2(s2[cc], w2p[3 * 16 + cc], b3f, false);
            b4f = __builtin_amdgcn_fdot2(s2[cc], w2p[4 * 16 + cc], b4f, false);
            b5f = __builtin_amdgcn_fdot2(s2[cc], w2p[5 * 16 + cc], b5f, false);
            b6f = __builtin_amdgcn_fdot2(s2[cc], w2p[6 * 16 + cc], b6f, false);
            b7f = __builtin_amdgcn_fdot2(s2[cc], w2p[7 * 16 + cc], b7f, false);
        }
        br.x = f2bf(b0f) | (f2bf(b1f) << 16);
        br.y = f2bf(b2f) | (f2bf(b3f) << 16);
        br.z = f2bf(b4f) | (f2bf(b5f) << 16);
        br.w = f2bf(b6f) | (f2bf(b7f) << 16);
        const int lp = base[b] + atomicAdd(&cnt[b], 1);
        if (lp < ACAP) {
            A_rec[(size_t)b * ACAP + lp]  = ((unsigned)jl << 24) | (unsigned)i;
            A_bias[(size_t)b * ACAP + lp] = br;
        }
    }
}

// ---------------- K_B: per-bucket CSR finalize ----------------
// Per bucket: degree histogram + scan -> global offs; move records to
// globally-contiguous CSR positions (scatter window ~125 KB -> L2).
__global__ __launch_bounds__(512) void bucket_csr(
    const int* __restrict__ gcur,
    const unsigned int* __restrict__ A_rec, const uint4* __restrict__ A_bias,
    int* __restrict__ offs, int* __restrict__ src_sorted,
    uint4* __restrict__ bias_sorted)
{
    __shared__ int sc[256];
    __shared__ int ldeg[NPB];
    __shared__ int loff[NPB + 1];
    __shared__ int gbase_s;
    const int tid = threadIdx.x;
    const int b = blockIdx.x;
    // exclusive prefix over bucket counts -> this bucket's global base
    if (tid < 256) sc[tid] = min(gcur[tid], ACAP);
    __syncthreads();
    for (int o = 1; o < 256; o <<= 1) {
        int t = 0;
        if (tid < 256 && tid >= o) t = sc[tid - o];
        __syncthreads();
        if (tid < 256) sc[tid] += t;
        __syncthreads();
    }
    if (tid == 0) gbase_s = (b == 0) ? 0 : sc[b - 1];
    if (tid < NPB) ldeg[tid] = 0;
    __syncthreads();
    const int gbase = gbase_s;
    const int nb = min(gcur[b], ACAP);
    // degree histogram
    for (int r = tid; r < nb; r += 512)
        atomicAdd(&ldeg[A_rec[(size_t)b * ACAP + r] >> 24], 1);
    __syncthreads();
    // scan degrees -> local offsets
    if (tid < 256) sc[tid] = (tid < NPB) ? ldeg[tid] : 0;
    __syncthreads();
    for (int o = 1; o < 256; o <<= 1) {
        int t = 0;
        if (tid < 256 && tid >= o) t = sc[tid - o];
        __syncthreads();
        if (tid < 256) sc[tid] += t;
        __syncthreads();
    }
    if (tid == 0) loff[0] = 0;
    if (tid < NPB) { loff[tid + 1] = sc[tid]; ldeg[tid] = 0; }  // ldeg -> cursor
    __syncthreads();
    // global CSR offsets
    const int jbase = b * NPB;
    if (tid < NPB && jbase + tid < N_NODES) offs[jbase + tid] = gbase + loff[tid];
    if (b == NB - 1 && tid == 0) offs[N_NODES] = gbase + nb;
    // move records into CSR order
    for (int r = tid; r < nb; r += 512) {
        const unsigned int rec = A_rec[(size_t)b * ACAP + r];
        const int jl = rec >> 24;
        const int slot = loff[jl] + atomicAdd(&ldeg[jl], 1);
        const int gp = gbase + slot;
        src_sorted[gp] = (int)(rec & 0xFFFFFFu);
        bias_sorted[gp] = A_bias[(size_t)b * ACAP + r];
    }
}

// ---------------- K1: Q/K/V projections; K,V packed bf16 into one uint row ----------------
__global__ __launch_bounds__(256) void qkv_proj(
    const float* __restrict__ x,
    const float* __restrict__ WQ, const float* __restrict__ bQ,
    const float* __restrict__ WK, const float* __restrict__ bK,
    const float* __restrict__ WV, const float* __restrict__ bV,
    float* __restrict__ Q, unsigned int* __restrict__ KV)
{
    __shared__ float sWQ[DIM * DIM];
    __shared__ float sWK[DIM * DIM];
    __shared__ float sWV[DIM * DIM];
    for (int t = threadIdx.x; t < DIM * DIM; t += blockDim.x) {
        sWQ[t] = WQ[t]; sWK[t] = WK[t]; sWV[t] = WV[t];
    }
    __syncthreads();
    const int lane = threadIdx.x & 63;
    const int wave = threadIdx.x >> 6;
    const int n = blockIdx.x * 4 + wave;
    if (n >= N_NODES) return;
    float xl = x[(size_t)n * DIM + lane];
    float aq = bQ[lane], ak = bK[lane], av = bV[lane];
    #pragma unroll
    for (int k = 0; k < DIM; ++k) {
        float xv = __shfl(xl, k, 64);
        aq += xv * sWQ[k * DIM + lane];
        ak += xv * sWK[k * DIM + lane];
        av += xv * sWV[k * DIM + lane];
    }
    Q[(size_t)n * DIM + lane] = aq;
    KV[(size_t)n * DIM + lane] = f2bf(ak) | (f2bf(av) << 16);  // K lo, V hi
}

// ---------------- K3: per-node attention + fused output projection ----------------
__global__ __launch_bounds__(256) void node_attn_out(
    const int* __restrict__ off,
    const int* __restrict__ src_sorted,
    const unsigned short* __restrict__ bias_u16,
    const float* __restrict__ Q, const unsigned int* __restrict__ KV,
    const float* __restrict__ WO, const float* __restrict__ bO,
    float* __restrict__ out)
{
    __shared__ float sWO[DIM * DIM];
    for (int t = threadIdx.x; t < DIM * DIM; t += 256) sWO[t] = WO[t];
    __syncthreads();
    const int lane = threadIdx.x & 63;
    const int wave = threadIdx.x >> 6;
    const int j = blockIdx.x * 4 + wave;
    if (j >= N_NODES) return;
    const int beg = off[j], end = off[j + 1];
    const int h = lane >> 3;
    const float qv = Q[(size_t)j * DIM + lane];
    const float inv_sqrt_dk = 0.35355339059327373f;
    float num = 0.0f;
    float den = 1e-12f;
    int t = beg;
    for (; t + 3 < end; t += 4) {
        const int i0 = src_sorted[t + 0];
        const int i1 = src_sorted[t + 1];
        const int i2 = src_sorted[t + 2];
        const int i3 = src_sorted[t + 3];
        const unsigned int u0 = KV[(size_t)i0 * DIM + lane];
        const unsigned int u1 = KV[(size_t)i1 * DIM + lane];
        const unsigned int u2 = KV[(size_t)i2 * DIM + lane];
        const unsigned int u3 = KV[(size_t)i3 * DIM + lane];
        const float b0 = bf_lo((unsigned int)bias_u16[(size_t)(t + 0) * HEADS + h]);
        const float b1 = bf_lo((unsigned int)bias_u16[(size_t)(t + 1) * HEADS + h]);
        const float b2 = bf_lo((unsigned int)bias_u16[(size_t)(t + 2) * HEADS + h]);
        const float b3 = bf_lo((unsigned int)bias_u16[(size_t)(t + 3) * HEADS + h]);
        float d0 = qv * bf_lo(u0);
        float d1 = qv * bf_lo(u1);
        float d2 = qv * bf_lo(u2);
        float d3 = qv * bf_lo(u3);
        d0 += __shfl_xor(d0, 1, 64); d1 += __shfl_xor(d1, 1, 64);
        d2 += __shfl_xor(d2, 1, 64); d3 += __shfl_xor(d3, 1, 64);
        d0 += __shfl_xor(d0, 2, 64); d1 += __shfl_xor(d1, 2, 64);
        d2 += __shfl_xor(d2, 2, 64); d3 += __shfl_xor(d3, 2, 64);
        d0 += __shfl_xor(d0, 4, 64); d1 += __shfl_xor(d1, 4, 64);
        d2 += __shfl_xor(d2, 4, 64); d3 += __shfl_xor(d3, 4, 64);
        const float e0 = __expf(d0 * inv_sqrt_dk + b0);
        const float e1 = __expf(d1 * inv_sqrt_dk + b1);
        const float e2 = __expf(d2 * inv_sqrt_dk + b2);
        const float e3 = __expf(d3 * inv_sqrt_dk + b3);
        num += e0 * bf_hi(u0) + e1 * bf_hi(u1) + e2 * bf_hi(u2) + e3 * bf_hi(u3);
        den += e0 + e1 + e2 + e3;
    }
    for (; t < end; ++t) {
        const int i0 = src_sorted[t];
        const unsigned int u0 = KV[(size_t)i0 * DIM + lane];
        const float b0 = bf_lo((unsigned int)bias_u16[(size_t)t * HEADS + h]);
        float d0 = qv * bf_lo(u0);
        d0 += __shfl_xor(d0, 1, 64);
        d0 += __shfl_xor(d0, 2, 64);
        d0 += __shfl_xor(d0, 4, 64);
        const float e0 = __expf(d0 * inv_sqrt_dk + b0);
        num += e0 * bf_hi(u0);
        den += e0;
    }
    const float av = num / den;
    float acc = bO[lane];
    #pragma unroll
    for (int k = 0; k < DIM; ++k) {
        acc += __shfl(av, k, 64) * sWO[k * DIM + lane];
    }
    out[(size_t)j * DIM + lane] = acc;
}

extern "C" void kernel_launch(void* const* d_in, const int* in_sizes, int n_in,
                              void* d_out, int out_size, void* d_ws, size_t ws_size,
                              hipStream_t stream) {
    const float* x    = (const float*)d_in[0];
    const int*   ei   = (const int*)d_in[1];
    const float* ea   = (const float*)d_in[2];
    const float* WQ   = (const float*)d_in[3];
    const float* bQ   = (const float*)d_in[4];
    const float* WK   = (const float*)d_in[5];
    const float* bK   = (const float*)d_in[6];
    const float* WV   = (const float*)d_in[7];
    const float* bV   = (const float*)d_in[8];
    const float* WO   = (const float*)d_in[9];
    const float* bO   = (const float*)d_in[10];
    const float* We1  = (const float*)d_in[11];
    const float* be1  = (const float*)d_in[12];
    const float* We2  = (const float*)d_in[13];
    const float* be2  = (const float*)d_in[14];
    float* out = (float*)d_out;

    char* ws = (char*)d_ws;
    size_t off_b = 0;
    auto alloc = [&](size_t bytes) {
        void* p = ws + off_b;
        off_b += (bytes + 255) & ~(size_t)255;
        return p;
    };
    float*        Q           = (float*)alloc((size_t)N_NODES * DIM * sizeof(float));
    unsigned int* KV          = (unsigned int*)alloc((size_t)N_NODES * DIM * sizeof(unsigned int));
    unsigned int* A_rec       = (unsigned int*)alloc((size_t)NB * ACAP * sizeof(unsigned int));
    uint4*        A_bias      = (uint4*)alloc((size_t)NB * ACAP * sizeof(uint4));
    int*          src_sorted  = (int*)alloc((size_t)N_EDGES * sizeof(int));
    uint4*        bias_sorted = (uint4*)alloc((size_t)N_EDGES * sizeof(uint4));
    int*          offs        = (int*)alloc((size_t)(N_NODES + 1) * sizeof(int));
    int*          gcur        = (int*)alloc((size_t)NB * sizeof(int));
    h2*           w1p         = (h2*)alloc(512 * sizeof(h2));
    h2*           w2p         = (h2*)alloc(128 * sizeof(h2));

    (void)hipMemsetAsync(gcur, 0, (size_t)NB * sizeof(int), stream);

    pack_weights<<<1, 1024, 0, stream>>>(We1, We2, w1p, w2p);
    mlp_partition<<<(N_EDGES + PART_E - 1) / PART_E, PART_T, 0, stream>>>(
        ei, ea, w1p, be1, w2p, be2, gcur, A_rec, A_bias);
    bucket_csr<<<NB, 512, 0, stream>>>(gcur, A_rec, A_bias,
                                       offs, src_sorted, bias_sorted);
    qkv_proj<<<(N_NODES + 3) / 4, 256, 0, stream>>>(x, WQ, bQ, WK, bK, WV, bV, Q, KV);
    node_attn_out<<<(N_NODES + 3) / 4, 256, 0, stream>>>(offs, src_sorted,
                                                         (const unsigned short*)bias_sorted,
                                                         Q, KV, WO, bO, out);
}